// Round 4
// baseline (413.455 us; speedup 1.0000x reference)
//
#include <hip/hip_runtime.h>
#include <math.h>

// VQ-VAE vector quantizer for MI355X.
// z: [32, 64, 64, 64] fp32 (B, C=D, H, W), embedding: [1024, 64] fp32.
// Outputs (concatenated fp32 in d_out):
//   [0 .. 8388607]  quantized, layout (b, c, h, w)
//   [8388608]       loss = L + 0.25*L, L = mean((q - z)^2)
//   [8388609]       perplexity
//   [8388610 .. ]   encoding indices (as float), 131072 of them
//
// Numerics: replicate numpy's fp32 arithmetic bit-for-bit where it affects
// argmin ordering (pairwise sums, sequential-FMA dot, op order of
// (zz+ee)-2*dot), since reference distances are quantized at ulp(64).
//
// Round 4: rounds 2-3 were LDS-throughput + VALU ADDITIVE (263us ~= 164 LDS
// + 125 VALU, phases barrier-aligned -> no overlap). New structure: 1 thread
// = 1 z-row held in 64 VGPRs (coalesced load: lane dim == w); k-loop reads
// emb[k] at a WAVE-UNIFORM address -> scalar-pipe broadcast loads (SGPR
// operand into v_fma), zero LDS in the hot loop. VALU floor 109us. Kernel B
// fused in (z already in regs); counts via LDS histogram.

#define NROWS 131072
#define KCODES 1024
#define DDIM 64

// Prevent fp contraction (hipcc defaults to -ffp-contract=fast which would
// fuse mul+add into fma and change bits vs numpy's separate mul/add).
__device__ __forceinline__ float nofuse(float x) {
    asm("" : "+v"(x));
    return x;
}

// numpy pairwise_sum for n=64 of terms a[i]*a[i] (8-stripe + fixed tree),
// with separate mul-round then add-round per term.
template <typename F>
__device__ __forceinline__ float pairwise64_sq(F load) {
    float r[8];
#pragma unroll
    for (int j = 0; j < 8; j++) {
        float v = load(j);
        r[j] = nofuse(v * v);
    }
#pragma unroll
    for (int i = 8; i < 64; i += 8) {
#pragma unroll
        for (int j = 0; j < 8; j++) {
            float v = load(i + j);
            r[j] = r[j] + nofuse(v * v);
        }
    }
    return ((r[0] + r[1]) + (r[2] + r[3])) + ((r[4] + r[5]) + (r[6] + r[7]));
}

// --- kernel A0: ee[k] = sum(e[k,:]**2) numpy-pairwise ---
__global__ __launch_bounds__(256) void kA0(const float* __restrict__ emb,
                                           float* __restrict__ ee) {
    int k = blockIdx.x * 256 + threadIdx.x;
    if (k >= KCODES) return;
    const float* er = emb + (size_t)k * DDIM;
    ee[k] = pairwise64_sq([&](int i) { return er[i]; });
}

// --- kernel A: fused argmin + quantized gather/store + loss + counts ---
// One thread per row n=(b,h,w); wave lanes = consecutive w -> all global
// z access coalesced. e-row address uniform across the wave.
__global__ __launch_bounds__(256) void kA(const float* __restrict__ z,
                                          const float* __restrict__ emb,
                                          const float* __restrict__ ee,
                                          int* __restrict__ counts,
                                          float* __restrict__ out_idx,
                                          float* __restrict__ out_q,
                                          double* __restrict__ loss_sum) {
    __shared__ int hist[KCODES];
    __shared__ double wred[4];
    const int tid = threadIdx.x;
    const int n = blockIdx.x * 256 + tid;
    const int w = n & 63;
    const int h = (n >> 6) & 63;
    const int b = n >> 12;

    const float* zb = z + (size_t)b * 262144 + (size_t)h * 64 + w;
    float zr[64];
#pragma unroll
    for (int d = 0; d < 64; d++) zr[d] = zb[(size_t)d * 4096];

    const float zz = pairwise64_sq([&](int i) { return zr[i]; });

#pragma unroll
    for (int s = 0; s < 4; s++) hist[tid + s * 256] = 0;
    __syncthreads();

    float minv = INFINITY;
    int mini = 0;
    for (int k = 0; k < KCODES; k++) {
        const float4* er = (const float4*)(emb + (size_t)k * 64);
        float dot = 0.0f;
#pragma unroll
        for (int q = 0; q < 16; q++) {
            float4 e4 = er[q];
            // sequential ascending-d FMA chain (matches BLAS sgemm)
            dot = __builtin_fmaf(zr[4 * q + 0], e4.x, dot);
            dot = __builtin_fmaf(zr[4 * q + 1], e4.y, dot);
            dot = __builtin_fmaf(zr[4 * q + 2], e4.z, dot);
            dot = __builtin_fmaf(zr[4 * q + 3], e4.w, dot);
        }
        float tt = zz + ee[k];        // fp32 add, rounds at ulp(~64)
        float dv = tt - 2.0f * dot;   // 2*dot exact; single sub round
        if (dv < minv) { minv = dv; mini = k; }  // strict < : first min wins
    }

    out_idx[n] = (float)mini;
    atomicAdd(&hist[mini], 1);

    // gather quantized row, store (b,c,h,w), accumulate fp64 loss
    const float4* qrow = (const float4*)(emb + (size_t)mini * 64);
    float* qb = out_q + (size_t)b * 262144 + (size_t)h * 64 + w;
    double dsum = 0.0;
#pragma unroll
    for (int q = 0; q < 16; q++) {
        float4 q4 = qrow[q];
        qb[(size_t)(4 * q + 0) * 4096] = q4.x;
        qb[(size_t)(4 * q + 1) * 4096] = q4.y;
        qb[(size_t)(4 * q + 2) * 4096] = q4.z;
        qb[(size_t)(4 * q + 3) * 4096] = q4.w;
        float d0 = q4.x - zr[4 * q + 0];
        float d1 = q4.y - zr[4 * q + 1];
        float d2 = q4.z - zr[4 * q + 2];
        float d3 = q4.w - zr[4 * q + 3];
        dsum += (double)(d0 * d0);
        dsum += (double)(d1 * d1);
        dsum += (double)(d2 * d2);
        dsum += (double)(d3 * d3);
    }
    for (int off = 32; off > 0; off >>= 1) dsum += __shfl_down(dsum, off, 64);
    __syncthreads();  // hist atomics done before flush reads
    if ((tid & 63) == 0) wred[tid >> 6] = dsum;
#pragma unroll
    for (int s = 0; s < 4; s++) {
        int slot = tid + s * 256;
        int c = hist[slot];
        if (c) atomicAdd(&counts[slot], c);
    }
    __syncthreads();
    if (tid == 0) {
        double tot = (wred[0] + wred[1]) + (wred[2] + wred[3]);
        atomicAdd(loss_sum, tot);
    }
}

// --- kernel C: loss + perplexity scalars ---
__global__ __launch_bounds__(1024) void kC(const int* __restrict__ counts,
                                           const double* __restrict__ loss_sum,
                                           float* __restrict__ out_loss,
                                           float* __restrict__ out_perp) {
    __shared__ float wr[16];
    const int tid = threadIdx.x;
    float p = (float)counts[tid] * (1.0f / 131072.0f);
    float v = p + 1e-10f;
    float term = p * logf(v);
    float s = term;
    for (int off = 32; off > 0; off >>= 1) s += __shfl_down(s, off, 64);
    if ((tid & 63) == 0) wr[tid >> 6] = s;
    __syncthreads();
    if (tid == 0) {
        float tot = 0.0f;
#pragma unroll
        for (int j = 0; j < 16; j++) tot += wr[j];
        out_perp[0] = expf(-tot);
        double L = *loss_sum / 8388608.0;
        float Lf = (float)L;
        out_loss[0] = Lf + 0.25f * Lf;
    }
}

extern "C" void kernel_launch(void* const* d_in, const int* in_sizes, int n_in,
                              void* d_out, int out_size, void* d_ws, size_t ws_size,
                              hipStream_t stream) {
    const float* z = (const float*)d_in[0];
    const float* emb = (const float*)d_in[1];
    float* out = (float*)d_out;
    float* out_q = out;                    // 8388608
    float* out_loss = out + 8388608;       // 1
    float* out_perp = out + 8388609;       // 1
    float* out_idx = out + 8388610;        // 131072

    char* ws = (char*)d_ws;
    double* loss_sum = (double*)ws;        // 8 B @ 0
    int* counts = (int*)(ws + 64);         // 4 KB @ 64
    float* ee = (float*)(ws + 64 + 4096);  // 4 KB

    hipMemsetAsync(d_ws, 0, 64 + 4096, stream);
    kA0<<<4, 256, 0, stream>>>(emb, ee);
    kA<<<512, 256, 0, stream>>>(z, emb, ee, counts, out_idx, out_q, loss_sum);
    kC<<<1, 1024, 0, stream>>>(counts, loss_sum, out_loss, out_perp);
}